// Round 11
// baseline (150.095 us; speedup 1.0000x reference)
//
#include <hip/hip_runtime.h>
#include <hip/hip_bf16.h>

// Problem: B=2, S=2048, D=256, H=8.
// out[b,h,s,:] = sum_{t<=s} exp( max(d2(s,t),0) / (2*gamma_h - 1e-6) ) * V[b,t,:]
// d2(s,t) = |Q_s|^2 + |K_t|^2 - 2 Q_s.K_t ; Q=p@Wq, K=p@Wk, V=e@Wv.
// Heads with equal gamma produce identical outputs -> dedupe by representative.
//
// R7: fragment-major operands.  R8: split partials + reduce (136us).
// R9/R10/R12/R13/R15: regressions, reverted.  R11: dual-tile ILP (131.8).
// R14: gemm bounds(256,3) + XCD-local p/e decode: 128.0 (best).
// R16/R17: scores||PV single-BB pipeline: 127.0 (+1 only) -> loads were
// already batched by the compiler; flash is bound by per-CU L2 delivery of
// the 96KB/visit K/V stream, whose latency the dependent score MFMAs expose.
// R18: K (hi+lo, 64KB/tile) prefetched ONE VISIT AHEAD via async
// global_load_lds into 128KB double-buffered LDS (vmcnt drain at the visit
// barrier is then ~free); scores read K via conflict-free ds_read_b128.
// V double-buffered in regs, issued one visit ahead.  3-acc score split
// (6 indep chains).  Single-tile visits, same pairing/splits/barrier count.

#define BB   2
#define SS   2048
#define DD   256
#define HH   8
#define BSR  (BB*SS)        // 4096 rows
#define TSPLIT 4

typedef __bf16 bf16_t;
typedef __bf16 bf16x8 __attribute__((ext_vector_type(8)));
typedef float  f32x4  __attribute__((ext_vector_type(4)));

static __device__ __forceinline__ f32x4 mfma16(bf16x8 a, bf16x8 b, f32x4 c) {
    return __builtin_amdgcn_mfma_f32_16x16x32_bf16(a, b, c, 0, 0, 0);
}

// async global->LDS copy, 16B per lane; lds dst is wave-uniform base,
// HW adds lane*16; global src is per-lane.
static __device__ __forceinline__ void gld_lds16(const bf16_t* g, bf16_t* l) {
    __builtin_amdgcn_global_load_lds(
        (const __attribute__((address_space(1))) unsigned int*)(unsigned long long)g,
        (__attribute__((address_space(3))) unsigned int*)(unsigned int)(unsigned long long)l,
        16, 0, 0);
}

// ---------------------------------------------------------------------------
// K0: W -> fragment-major WF (hi/lo split), plus q2/k2 zeroing (block 48).
// ---------------------------------------------------------------------------
__global__ __launch_bounds__(256) void att_wtrans(
    const float* __restrict__ Wq, const float* __restrict__ Wk,
    const float* __restrict__ Wv,
    bf16_t* __restrict__ WFq_h, bf16_t* __restrict__ WFq_l,
    bf16_t* __restrict__ WFk_h, bf16_t* __restrict__ WFk_l,
    bf16_t* __restrict__ WFv, float* __restrict__ q2, float* __restrict__ k2)
{
    __shared__ float tT[64][68];    // [n_local][k_local], pad 68
    const int tid = threadIdx.x;
    if (blockIdx.x == 48) {         // zero q2/k2 (gemm accumulates atomically)
        for (int i = tid; i < BSR; i += 256) { q2[i] = 0.f; k2[i] = 0.f; }
        return;
    }
    const int mat = blockIdx.x >> 4;        // 0=Wq 1=Wk 2=Wv
    const int tl  = blockIdx.x & 15;
    const int tr  = (tl >> 2) * 64, tc = (tl & 3) * 64;  // k-range, n-range
    const float* W = (mat == 0) ? Wq : ((mat == 1) ? Wk : Wv);

    // load W[k][n] tile rows coalesced, scatter transposed into LDS
#pragma unroll
    for (int i = 0; i < 4; ++i) {
        const int fidx = i * 256 + tid;     // [0,1024) float4 units
        const int r  = fidx >> 4;           // k_local
        const int c4 = fidx & 15;           // n_local/4
        const float4 v = *(const float4*)(W + (size_t)(tr + r) * DD + tc + c4 * 4);
        tT[c4 * 4 + 0][r] = v.x; tT[c4 * 4 + 1][r] = v.y;
        tT[c4 * 4 + 2][r] = v.z; tT[c4 * 4 + 3][r] = v.w;
    }
    __syncthreads();

#pragma unroll
    for (int i = 0; i < 2; ++i) {
        const int uidx  = i * 256 + tid;    // [0,512) 16B units
        const int chunk = uidx >> 6;        // kc_l(2) x c16(4)
        const int kc_l  = chunk >> 2, c16 = chunk & 3;
        const int u = uidx & 63, m16 = u & 15, quad = u >> 4;
        const float* src = &tT[c16 * 16 + m16][kc_l * 32 + quad * 8];
        const float4 a = *(const float4*)src;
        const float4 bq = *(const float4*)(src + 4);
        const float f[8] = {a.x, a.y, a.z, a.w, bq.x, bq.y, bq.z, bq.w};
        bf16x8 hi, lo;
#pragma unroll
        for (int j = 0; j < 8; ++j) {
            const bf16_t h = (bf16_t)f[j];
            hi[j] = h; lo[j] = (bf16_t)(f[j] - (float)h);
        }
        const int g16 = (tc >> 4) + c16;
        const int kcg = (tr >> 5) + kc_l;
        const size_t off = ((size_t)(g16 * 8 + kcg)) * 512 + (size_t)u * 8;
        if (mat == 0)      { *(bf16x8*)(WFq_h + off) = hi; *(bf16x8*)(WFq_l + off) = lo; }
        else if (mat == 1) { *(bf16x8*)(WFk_h + off) = hi; *(bf16x8*)(WFk_l + off) = lo; }
        else               { *(bf16x8*)(WFv + off)  = hi; }
    }
}

// ---------------------------------------------------------------------------
// K1: fused QKV projection via MFMA + DIRECT fragment-major epilogue.
// R14: bounds(256,3); bijective XCD-local decode.
// ---------------------------------------------------------------------------
__global__ __launch_bounds__(256, 3) void att_gemm_qkv(
    const float* __restrict__ p, const float* __restrict__ e,
    const bf16_t* __restrict__ WFq_h, const bf16_t* __restrict__ WFq_l,
    const bf16_t* __restrict__ WFk_h, const bf16_t* __restrict__ WFk_l,
    const bf16_t* __restrict__ WFv,
    bf16_t* __restrict__ QFh, bf16_t* __restrict__ QFl,
    bf16_t* __restrict__ KFh, bf16_t* __restrict__ KFl,
    bf16_t* __restrict__ VF, float* __restrict__ q2, float* __restrict__ k2)
{
    __shared__ float pL[16][264];
    __shared__ float eL[16][264];
    __shared__ float fQ[16][68];
    __shared__ float fK[16][68];
    __shared__ float fV[16][68];

    const int tid  = threadIdx.x;
    const int w    = tid >> 6;
    const int lane = tid & 63;
    const int m16  = lane & 15;
    const int quad = lane >> 4;
    const int xcd  = blockIdx.x & 7;
    const int jid  = blockIdx.x >> 3;      // [0,128)
    const int nb   = jid >> 5;             // [0,4)
    const int row0 = (xcd * 32 + (jid & 31)) * 16;

    // stage p/e tiles (16 rows x 256 cols), coalesced
#pragma unroll
    for (int i = 0; i < 4; ++i) {
        const int fidx = i * 256 + tid;     // [0,1024) float4
        const int r  = fidx >> 6;
        const int c4 = fidx & 63;
        const float4 pv = *(const float4*)(p + (size_t)(row0 + r) * DD + c4 * 4);
        const float4 ev = *(const float4*)(e + (size_t)(row0 + r) * DD + c4 * 4);
        *(float4*)&pL[r][c4 * 4] = pv;
        *(float4*)&eL[r][c4 * 4] = ev;
    }
    __syncthreads();

    f32x4 aQ = f32x4{0.f, 0.f, 0.f, 0.f};
    f32x4 aK = f32x4{0.f, 0.f, 0.f, 0.f};
    f32x4 aV = f32x4{0.f, 0.f, 0.f, 0.f};

#pragma unroll 2
    for (int kc = 0; kc < 8; ++kc) {
        const float* ps = &pL[m16][kc * 32 + quad * 8];
        const float* es = &eL[m16][kc * 32 + quad * 8];
        const float4 p0 = *(const float4*)ps;
        const float4 p1 = *(const float4*)(ps + 4);
        const float4 e0 = *(const float4*)es;
        const float4 e1 = *(const float4*)(es + 4);
        const float pa[8] = {p0.x, p0.y, p0.z, p0.w, p1.x, p1.y, p1.z, p1.w};
        const float ea[8] = {e0.x, e0.y, e0.z, e0.w, e1.x, e1.y, e1.z, e1.w};
        bf16x8 aph, apl, aeb;
#pragma unroll
        for (int j = 0; j < 8; ++j) {
            const bf16_t h = (bf16_t)pa[j];
            aph[j] = h;
            apl[j] = (bf16_t)(pa[j] - (float)h);
            aeb[j] = (bf16_t)ea[j];
        }
        const size_t wo = ((size_t)((nb * 4 + w) * 8 + kc)) * 512 + (size_t)lane * 8;
        const bf16x8 bqh = *(const bf16x8*)(WFq_h + wo);
        const bf16x8 bql = *(const bf16x8*)(WFq_l + wo);
        const bf16x8 bkh = *(const bf16x8*)(WFk_h + wo);
        const bf16x8 bkl = *(const bf16x8*)(WFk_l + wo);
        const bf16x8 bv  = *(const bf16x8*)(WFv + wo);
        aQ = mfma16(aph, bqh, aQ);
        aQ = mfma16(apl, bqh, aQ);
        aQ = mfma16(aph, bql, aQ);
        aK = mfma16(aph, bkh, aK);
        aK = mfma16(apl, bkh, aK);
        aK = mfma16(aph, bkl, aK);
        aV = mfma16(aeb, bv, aV);
    }

    // stage accumulators f32 into LDS for the fragment transpose
#pragma unroll
    for (int r = 0; r < 4; ++r) {
        const int rl = quad * 4 + r;          // C/D row = quad*4+reg
        fQ[rl][w * 16 + m16] = aQ[r];
        fK[rl][w * 16 + m16] = aK[r];
        fV[rl][w * 16 + m16] = aV[r];
    }

    // q2/k2 row-norm partials (from f32 accumulators)
#pragma unroll
    for (int r = 0; r < 4; ++r) {
        float vq = aQ[r] * aQ[r], vk = aK[r] * aK[r];
#pragma unroll
        for (int off = 8; off >= 1; off >>= 1) {
            vq += __shfl_xor(vq, off);
            vk += __shfl_xor(vk, off);
        }
        if (m16 == 0) {
            atomicAdd(q2 + row0 + quad * 4 + r, vq);
            atomicAdd(k2 + row0 + quad * 4 + r, vk);
        }
    }

    __syncthreads();

    const int b   = row0 >> 11;
    const int sl  = row0 & 2047;
    const int tt  = sl >> 6;
    const int st  = sl >> 5;
    const int w4  = (sl >> 4) & 3;   // KF row-group
    const int mt  = (sl >> 4) & 1;   // QF row-group
    const int kc2 = (sl >> 5) & 1;   // VF t-half
    const int uh  = (sl >> 4) & 1;   // VF u-half

    if (w < 2) {
        // QF chunk kc = nb*2 + w  (hi + lo)
        const int cl = w;
        const float* src = &fQ[m16][cl * 32 + quad * 8];
        const float4 a = *(const float4*)src;
        const float4 c = *(const float4*)(src + 4);
        const float f[8] = {a.x, a.y, a.z, a.w, c.x, c.y, c.z, c.w};
        bf16x8 hi, lo;
#pragma unroll
        for (int j = 0; j < 8; ++j) {
            const bf16_t h = (bf16_t)f[j];
            hi[j] = h; lo[j] = (bf16_t)(f[j] - (float)h);
        }
        const size_t off = ((size_t)(b * 64 + st)) * 8192
                         + (size_t)(mt * 8 + nb * 2 + cl) * 512 + (size_t)lane * 8;
        *(bf16x8*)(QFh + off) = hi; *(bf16x8*)(QFl + off) = lo;
    } else {
        // KF chunk kc = nb*2 + (w-2)  (hi + lo)
        const int cl = w - 2;
        const float* src = &fK[m16][cl * 32 + quad * 8];
        const float4 a = *(const float4*)src;
        const float4 c = *(const float4*)(src + 4);
        const float f[8] = {a.x, a.y, a.z, a.w, c.x, c.y, c.z, c.w};
        bf16x8 hi, lo;
#pragma unroll
        for (int j = 0; j < 8; ++j) {
            const bf16_t h = (bf16_t)f[j];
            hi[j] = h; lo[j] = (bf16_t)(f[j] - (float)h);
        }
        const size_t off = ((size_t)(b * 32 + tt)) * 16384
                         + (size_t)(w4 * 8 + nb * 2 + cl) * 512 + (size_t)lane * 8;
        *(bf16x8*)(KFh + off) = hi; *(bf16x8*)(KFl + off) = lo;
    }

    // VF half-chunks: wave w handles nt=w with lanes 0..31 (u-half uh)
    if (lane < 32) {
        const int nt  = w;
        const int u   = uh * 32 + lane;
        const int tl0 = (lane >> 4) * 8;     // t_local base within block rows
        bf16x8 vb;
#pragma unroll
        for (int j = 0; j < 8; ++j)
            vb[j] = (bf16_t)fV[tl0 + j][nt * 16 + (lane & 15)];
        const size_t off = ((size_t)(b * 32 + tt)) * 16384
                         + (size_t)(nb * 8 + kc2 * 4 + nt) * 512 + (size_t)u * 8;
        *(bf16x8*)(VF + off) = vb;
    }
}

// ---------------------------------------------------------------------------
// K2: flash-style causal pass.  Grid = 256 (32 pairs x 4 splits x 2 b),
// bid&7 == split*2+b (one class per XCD; K/V set fits its L2).
// R18: single-tile visits.  K(t+1) DMA'd one visit ahead into 128KB
// double-buffered LDS (global_load_lds w16); V(t+1) reg-prefetched (vf[2]).
// Per visit: {DMA K(t+1); load V(t+1); scores(t) from LDS -> Pb[pb];
// barrier (drains DMA+V, publishes Pb); PV(t)}.  3-acc score split gives
// 6 independent MFMA chains.  Ascending tile order per split (same O order).
// ---------------------------------------------------------------------------
__global__ __launch_bounds__(256, 1) void att_flash(
    const bf16_t* __restrict__ QFh, const bf16_t* __restrict__ QFl,
    const bf16_t* __restrict__ KFh, const bf16_t* __restrict__ KFl,
    const bf16_t* __restrict__ VF, const float* __restrict__ q2,
    const float* __restrict__ k2, const float* __restrict__ gamma,
    float* __restrict__ part, float* __restrict__ out)
{
    __shared__ bf16_t Klds[2][2][16384];   // [parity][hi|lo][elem]  128 KB
    __shared__ bf16_t Pb[2][32][72];       // [parity][s][t]         9.2 KB

    const int tid   = threadIdx.x;
    const int pair  = blockIdx.x >> 3;     // 0..31
    const int sub   = blockIdx.x & 7;      // == xcd class
    const int split = sub >> 1;            // 0..3
    const int b     = sub & 1;
    const int wave  = tid >> 6;
    const int lane  = tid & 63;
    const int m16   = lane & 15;
    const int quad  = lane >> 4;

    float g[8];
#pragma unroll
    for (int h = 0; h < 8; ++h) g[h] = gamma[h];

    for (int half = 0; half < 2; ++half) {
        const int st = half ? (63 - pair) : pair;
        const int s0 = st * 32;

        // Q fragments -> registers, contiguous chunk loads.
        bf16x8 aQh[2][8], aQl[2][8];
        const size_t qtile = ((size_t)(b * 64 + st)) * 8192 + (size_t)lane * 8;
#pragma unroll
        for (int mt = 0; mt < 2; ++mt)
#pragma unroll
            for (int kc = 0; kc < 8; ++kc) {
                const size_t base = qtile + (size_t)(mt * 8 + kc) * 512;
                aQh[mt][kc] = *(const bf16x8*)(QFh + base);
                aQl[mt][kc] = *(const bf16x8*)(QFl + base);
            }

        float q2r[2][4];
#pragma unroll
        for (int mt = 0; mt < 2; ++mt)
#pragma unroll
            for (int r = 0; r < 4; ++r)
                q2r[mt][r] = q2[b * SS + s0 + mt * 16 + quad * 4 + r];

        const int n_tiles = (s0 + 31) / 64 + 1;

        for (int h = 0; h < HH; ++h) {
            int rep = 0;
            while (g[rep] != g[h]) ++rep;
            if (rep != h) continue;
            const float cexp = 1.0f / (2.0f * g[h] - 1e-6f);

            f32x4 O[2][4];
#pragma unroll
            for (int mt = 0; mt < 2; ++mt)
#pragma unroll
                for (int nt = 0; nt < 4; ++nt)
                    O[mt][nt] = f32x4{0.f, 0.f, 0.f, 0.f};

            bf16x8 vf[2][2][4];   // [slot][kc2][nt]

            // issue async K DMA for tile tiX into parity buffer par
            auto DMA_K = [&](int tiX, int par) {
                const size_t tb = ((size_t)(b * 32 + tiX)) * 16384
                                + (size_t)wave * 4096 + (size_t)lane * 8;
#pragma unroll
                for (int i = 0; i < 8; ++i) {
                    gld_lds16(KFh + tb + (size_t)i * 512,
                              &Klds[par][0][wave * 4096 + i * 512]);
                    gld_lds16(KFl + tb + (size_t)i * 512,
                              &Klds[par][1][wave * 4096 + i * 512]);
                }
            };

            auto LOADV = [&](int tiX, int slot) {
                const size_t tile = ((size_t)(b * 32 + tiX)) * 16384
                                  + (size_t)wave * 4096 + (size_t)lane * 8;
#pragma unroll
                for (int kc2 = 0; kc2 < 2; ++kc2)
#pragma unroll
                    for (int nt = 0; nt < 4; ++nt)
                        vf[slot][kc2][nt] = *(const bf16x8*)(
                            VF + tile + (size_t)(kc2 * 4 + nt) * 512);
            };

            // scores for tile tiX from LDS parity par -> Pb[pb]
            auto SCORES = [&](int tiX, int par, int pb) {
                const int tg = tiX * 64 + wave * 16 + m16;
                const float k2v = k2[b * SS + tg];
                f32x4 hh0 = f32x4{0.f, 0.f, 0.f, 0.f};
                f32x4 hh1 = f32x4{0.f, 0.f, 0.f, 0.f};
                f32x4 lh0 = f32x4{0.f, 0.f, 0.f, 0.f};
                f32x4 lh1 = f32x4{0.f, 0.f, 0.f, 0.f};
                f32x4 hl0 = f32x4{0.f, 0.f, 0.f, 0.f};
                f32x4 hl1 = f32x4{0.f, 0.f, 0.f, 0.f};
#pragma unroll
                for (int kc = 0; kc < 8; ++kc) {
                    const bf16x8 bh = *(const bf16x8*)
                        &Klds[par][0][wave * 4096 + kc * 512 + lane * 8];
                    const bf16x8 bl = *(const bf16x8*)
                        &Klds[par][1][wave * 4096 + kc * 512 + lane * 8];
                    hh0 = mfma16(aQh[0][kc], bh, hh0);
                    hh1 = mfma16(aQh[1][kc], bh, hh1);
                    lh0 = mfma16(aQl[0][kc], bh, lh0);
                    lh1 = mfma16(aQl[1][kc], bh, lh1);
                    hl0 = mfma16(aQh[0][kc], bl, hl0);
                    hl1 = mfma16(aQh[1][kc], bl, hl1);
                }
#pragma unroll
                for (int mt = 0; mt < 2; ++mt) {
#pragma unroll
                    for (int r = 0; r < 4; ++r) {
                        const int sl = mt * 16 + quad * 4 + r;
                        const int sg = s0 + sl;
                        const float dotv = mt ? (hh1[r] + lh1[r] + hl1[r])
                                              : (hh0[r] + lh0[r] + hl0[r]);
                        float d2 = q2r[mt][r] + k2v - 2.0f * dotv;
                        d2 = fmaxf(d2, 0.0f);
                        Pb[pb][sl][wave * 16 + m16] =
                            (bf16_t)((tg <= sg) ? __expf(cexp * d2) : 0.0f);
                    }
                }
            };

            auto PV = [&](int pb, int slot) {
#pragma unroll
                for (int kc2 = 0; kc2 < 2; ++kc2) {
                    const bf16x8 pa0 = *(const bf16x8*)
                        &Pb[pb][m16][kc2 * 32 + quad * 8];
                    const bf16x8 pa1 = *(const bf16x8*)
                        &Pb[pb][m16 + 16][kc2 * 32 + quad * 8];
#pragma unroll
                    for (int nt = 0; nt < 4; ++nt) {
                        O[0][nt] = mfma16(pa0, vf[slot][kc2][nt], O[0][nt]);
                        O[1][nt] = mfma16(pa1, vf[slot][kc2][nt], O[1][nt]);
                    }
                }
            };

            int ti = split;
            if (ti < n_tiles) {
                // prologue: stage first tile
                DMA_K(ti, 0);
                LOADV(ti, 0);
                __syncthreads();           // vmcnt(0) drain: K(ti)+V(ti) ready
                int par = 0, pb = 0, slot = 0;
                while (true) {
                    const int tn = ti + TSPLIT;
                    const bool more = (tn < n_tiles);
                    if (more) { DMA_K(tn, par ^ 1); LOADV(tn, slot ^ 1); }
                    SCORES(ti, par, pb);
                    __syncthreads();       // publish Pb[pb]; drain K(tn)+V(tn)
                    PV(pb, slot);
                    if (!more) break;
                    ti = tn; par ^= 1; pb ^= 1; slot ^= 1;
                }
            }
            __syncthreads();               // protect Pb/Klds across h/half

            // plain stores: split0 -> out slab, splits 1..3 -> ws partials
            float* dst = (split == 0)
                ? out  + (((size_t)b * HH + h) * SS + s0) * DD
                : part + ((((size_t)(split - 1) * BB + b) * HH + h) * SS + s0) * DD;
#pragma unroll
            for (int mt = 0; mt < 2; ++mt)
#pragma unroll
                for (int nt = 0; nt < 4; ++nt)
#pragma unroll
                    for (int r = 0; r < 4; ++r)
                        dst[(size_t)(mt * 16 + quad * 4 + r) * DD
                            + wave * 64 + nt * 16 + m16] = O[mt][nt][r];
        }
    }
}

// ---------------------------------------------------------------------------
// K3: reduce split partials into rep heads and broadcast to duplicate-gamma
// heads.  out[b][rep] already holds split0; add 3 partial slabs, write to
// every head sharing that gamma.
// ---------------------------------------------------------------------------
__global__ __launch_bounds__(256) void att_reduce_bcast(
    const float* __restrict__ gamma, const float* __restrict__ part,
    float* __restrict__ out)
{
    const int j = blockIdx.x * 256 + threadIdx.x;   // float4 index within slab
    const int b = blockIdx.y;
    const int slab = SS * DD / 4;

    float g[8];
#pragma unroll
    for (int h = 0; h < 8; ++h) g[h] = gamma[h];

    const float4* pp = (const float4*)part;
    float4* o4 = (float4*)out;

    float4 repval{0.f, 0.f, 0.f, 0.f};
    int last_rep = -1;
#pragma unroll
    for (int h = 0; h < HH; ++h) {
        int rep = 0;
        while (g[rep] != g[h]) ++rep;
        float4* o = o4 + ((size_t)(b * HH + h)) * slab + j;
        if (rep == h) {
            float4 v = *o;
#pragma unroll
            for (int k = 0; k < TSPLIT - 1; ++k) {
                const float4 pv = pp[(((size_t)k * BB + b) * HH + h) * slab + j];
                v.x += pv.x; v.y += pv.y; v.z += pv.z; v.w += pv.w;
            }
            *o = v; repval = v; last_rep = h;
        } else {
            if (last_rep != rep) {
                repval = o4[((size_t)(b * HH + rep)) * slab + j];
                last_rep = rep;
            }
            *o = repval;
        }
    }
}

extern "C" void kernel_launch(void* const* d_in, const int* in_sizes, int n_in,
                              void* d_out, int out_size, void* d_ws, size_t ws_size,
                              hipStream_t stream) {
    (void)in_sizes; (void)n_in; (void)out_size; (void)ws_size;
    // inputs: 0=x (unused), 1=e, 2=p, 3=W_q, 4=W_k, 5=W_v, 6=gamma
    const float* e     = (const float*)d_in[1];
    const float* p     = (const float*)d_in[2];
    const float* Wq    = (const float*)d_in[3];
    const float* Wk    = (const float*)d_in[4];
    const float* Wv    = (const float*)d_in[5];
    const float* gamma = (const float*)d_in[6];

    const size_t NROW = (size_t)BSR * DD;   // 1048576 elements
    bf16_t* WFq_h = (bf16_t*)d_ws;          // fragment-major weights
    bf16_t* WFq_l = WFq_h + DD * DD;
    bf16_t* WFk_h = WFq_l + DD * DD;
    bf16_t* WFk_l = WFk_h + DD * DD;
    bf16_t* WFv   = WFk_l + DD * DD;
    float*  q2    = (float*)(WFv + DD * DD);
    float*  k2    = q2 + BSR;
    bf16_t* QFh   = (bf16_t*)(k2 + BSR);    // fragment-major Q/K/V
    bf16_t* QFl   = QFh + NROW;
    bf16_t* KFh   = QFl + NROW;
    bf16_t* KFl   = KFh + NROW;
    bf16_t* VF    = KFl + NROW;
    float*  part  = (float*)(VF + NROW);    // 3 x B x H x S x D f32 (~101MB)

    float* out = (float*)d_out;

    att_wtrans<<<dim3(49), dim3(256), 0, stream>>>(
        Wq, Wk, Wv, WFq_h, WFq_l, WFk_h, WFk_l, WFv, q2, k2);

    att_gemm_qkv<<<dim3((BSR / 16) * 4), dim3(256), 0, stream>>>(
        p, e, WFq_h, WFq_l, WFk_h, WFk_l, WFv, QFh, QFl, KFh, KFl, VF, q2, k2);

    att_flash<<<dim3(32 * TSPLIT * BB), dim3(256), 0, stream>>>(
        QFh, QFl, KFh, KFl, VF, q2, k2, gamma, part, out);

    att_reduce_bcast<<<dim3(SS * DD / 4 / 256, BB), dim3(256), 0, stream>>>(
        gamma, part, out);
}

// Round 12
// 124.853 us; speedup vs baseline: 1.2022x; 1.2022x over previous
//
#include <hip/hip_runtime.h>
#include <hip/hip_bf16.h>

// Problem: B=2, S=2048, D=256, H=8.
// out[b,h,s,:] = sum_{t<=s} exp( max(d2(s,t),0) / (2*gamma_h - 1e-6) ) * V[b,t,:]
// d2(s,t) = |Q_s|^2 + |K_t|^2 - 2 Q_s.K_t ; Q=p@Wq, K=p@Wk, V=e@Wv.
// Heads with equal gamma produce identical outputs -> dedupe by representative.
//
// R7: fragment-major operands.  R8: split partials + reduce (136us).
// R9/R10/R12/R13/R15: regressions, reverted.  R11: dual-tile ILP (131.8).
// R14: gemm bounds(256,3) + XCD-local p/e decode (128.0).
// R16/R17: scores||PV single-BB pipeline (127.0, best).
// R18: DMA-K prefetch regressed (150): __syncthreads drains vmcnt(0), so the
//      "one visit ahead" DMA serialized into the same visit -> reverted.
// R19: gemm is repack-VALU-bound (~640 cyc/wave repack vs ~280 MFMA), and
//      each row-slice is repacked 4x (once per nb-block).  Hoist the bf16x3
//      repack into a pre-pass (ph/pl/eb arrays; IDENTICAL rounding ops ->
//      bit-identical Q/K/V) appended to att_wtrans's grid (49->305 blocks,
//      GPU idle there anyway).  gemm kc-loop: 3 LDS reads + 5 W loads +
//      7 MFMAs, zero conversions; staged LDS 32->24 KB.

#define BB   2
#define SS   2048
#define DD   256
#define HH   8
#define BSR  (BB*SS)        // 4096 rows
#define TSPLIT 4

typedef __bf16 bf16_t;
typedef __bf16 bf16x4 __attribute__((ext_vector_type(4)));
typedef __bf16 bf16x8 __attribute__((ext_vector_type(8)));
typedef float  f32x4  __attribute__((ext_vector_type(4)));

static __device__ __forceinline__ f32x4 mfma16(bf16x8 a, bf16x8 b, f32x4 c) {
    return __builtin_amdgcn_mfma_f32_16x16x32_bf16(a, b, c, 0, 0, 0);
}

// ---------------------------------------------------------------------------
// K0: blocks 0..47: W -> fragment-major WF (hi/lo split).  Block 48: zero
// q2/k2.  Blocks 49..304: repack p -> (ph,pl) and e -> eb  (bf16x3 split
// moved out of gemm; same rounding ops -> downstream bit-identical).
// ---------------------------------------------------------------------------
__global__ __launch_bounds__(256) void att_wtrans(
    const float* __restrict__ Wq, const float* __restrict__ Wk,
    const float* __restrict__ Wv, const float* __restrict__ p,
    const float* __restrict__ e,
    bf16_t* __restrict__ WFq_h, bf16_t* __restrict__ WFq_l,
    bf16_t* __restrict__ WFk_h, bf16_t* __restrict__ WFk_l,
    bf16_t* __restrict__ WFv, bf16_t* __restrict__ ph, bf16_t* __restrict__ pl,
    bf16_t* __restrict__ eb, float* __restrict__ q2, float* __restrict__ k2)
{
    __shared__ float tT[64][68];    // [n_local][k_local], pad 68
    const int tid = threadIdx.x;
    if (blockIdx.x == 48) {         // zero q2/k2 (gemm accumulates atomically)
        for (int i = tid; i < BSR; i += 256) { q2[i] = 0.f; k2[i] = 0.f; }
        return;
    }
    if (blockIdx.x >= 49) {         // p/e repack: 16 rows per block
        const size_t base = (size_t)(blockIdx.x - 49) * 16 * DD;
#pragma unroll
        for (int i = 0; i < 4; ++i) {
            const int u = i * 256 + tid;          // float4 unit in [0,1024)
            const float4 pv = *(const float4*)(p + base + (size_t)u * 4);
            const float4 ev = *(const float4*)(e + base + (size_t)u * 4);
            const float pf[4] = {pv.x, pv.y, pv.z, pv.w};
            const float ef[4] = {ev.x, ev.y, ev.z, ev.w};
            bf16x4 hv, lv, ebv;
#pragma unroll
            for (int j = 0; j < 4; ++j) {
                const bf16_t h = (bf16_t)pf[j];
                hv[j] = h; lv[j] = (bf16_t)(pf[j] - (float)h);
                ebv[j] = (bf16_t)ef[j];
            }
            *(bf16x4*)(ph + base + (size_t)u * 4) = hv;
            *(bf16x4*)(pl + base + (size_t)u * 4) = lv;
            *(bf16x4*)(eb + base + (size_t)u * 4) = ebv;
        }
        return;
    }
    const int mat = blockIdx.x >> 4;        // 0=Wq 1=Wk 2=Wv
    const int tl  = blockIdx.x & 15;
    const int tr  = (tl >> 2) * 64, tc = (tl & 3) * 64;  // k-range, n-range
    const float* W = (mat == 0) ? Wq : ((mat == 1) ? Wk : Wv);

    // load W[k][n] tile rows coalesced, scatter transposed into LDS
#pragma unroll
    for (int i = 0; i < 4; ++i) {
        const int fidx = i * 256 + tid;     // [0,1024) float4 units
        const int r  = fidx >> 4;           // k_local
        const int c4 = fidx & 15;           // n_local/4
        const float4 v = *(const float4*)(W + (size_t)(tr + r) * DD + tc + c4 * 4);
        tT[c4 * 4 + 0][r] = v.x; tT[c4 * 4 + 1][r] = v.y;
        tT[c4 * 4 + 2][r] = v.z; tT[c4 * 4 + 3][r] = v.w;
    }
    __syncthreads();

#pragma unroll
    for (int i = 0; i < 2; ++i) {
        const int uidx  = i * 256 + tid;    // [0,512) 16B units
        const int chunk = uidx >> 6;        // kc_l(2) x c16(4)
        const int kc_l  = chunk >> 2, c16 = chunk & 3;
        const int u = uidx & 63, m16 = u & 15, quad = u >> 4;
        const float* src = &tT[c16 * 16 + m16][kc_l * 32 + quad * 8];
        const float4 a = *(const float4*)src;
        const float4 bq = *(const float4*)(src + 4);
        const float f[8] = {a.x, a.y, a.z, a.w, bq.x, bq.y, bq.z, bq.w};
        bf16x8 hi, lo;
#pragma unroll
        for (int j = 0; j < 8; ++j) {
            const bf16_t h = (bf16_t)f[j];
            hi[j] = h; lo[j] = (bf16_t)(f[j] - (float)h);
        }
        const int g16 = (tc >> 4) + c16;
        const int kcg = (tr >> 5) + kc_l;
        const size_t off = ((size_t)(g16 * 8 + kcg)) * 512 + (size_t)u * 8;
        if (mat == 0)      { *(bf16x8*)(WFq_h + off) = hi; *(bf16x8*)(WFq_l + off) = lo; }
        else if (mat == 1) { *(bf16x8*)(WFk_h + off) = hi; *(bf16x8*)(WFk_l + off) = lo; }
        else               { *(bf16x8*)(WFv + off)  = hi; }
    }
}

// ---------------------------------------------------------------------------
// K1: fused QKV projection via MFMA + DIRECT fragment-major epilogue.
// R14: bounds(256,3); bijective XCD-local decode.  R19: A-operands arrive
// pre-repacked (ph/pl/eb bf16); kc loop has zero conversions.
// ---------------------------------------------------------------------------
__global__ __launch_bounds__(256, 3) void att_gemm_qkv(
    const bf16_t* __restrict__ ph, const bf16_t* __restrict__ pl,
    const bf16_t* __restrict__ eb,
    const bf16_t* __restrict__ WFq_h, const bf16_t* __restrict__ WFq_l,
    const bf16_t* __restrict__ WFk_h, const bf16_t* __restrict__ WFk_l,
    const bf16_t* __restrict__ WFv,
    bf16_t* __restrict__ QFh, bf16_t* __restrict__ QFl,
    bf16_t* __restrict__ KFh, bf16_t* __restrict__ KFl,
    bf16_t* __restrict__ VF, float* __restrict__ q2, float* __restrict__ k2)
{
    __shared__ bf16_t phL[16][264];
    __shared__ bf16_t plL[16][264];
    __shared__ bf16_t ebL[16][264];
    __shared__ float fQ[16][68];
    __shared__ float fK[16][68];
    __shared__ float fV[16][68];

    const int tid  = threadIdx.x;
    const int w    = tid >> 6;
    const int lane = tid & 63;
    const int m16  = lane & 15;
    const int quad = lane >> 4;
    const int xcd  = blockIdx.x & 7;
    const int jid  = blockIdx.x >> 3;      // [0,128)
    const int nb   = jid >> 5;             // [0,4)
    const int row0 = (xcd * 32 + (jid & 31)) * 16;

    // stage pre-repacked tiles (16 rows x 256 cols bf16 x 3), coalesced 16B
#pragma unroll
    for (int i = 0; i < 2; ++i) {
        const int u = i * 256 + tid;       // 16B unit in [0,512)
        const int r = u >> 5, c8 = u & 31;
        const size_t go = (size_t)(row0 + r) * DD + c8 * 8;
        *(bf16x8*)&phL[r][c8 * 8] = *(const bf16x8*)(ph + go);
        *(bf16x8*)&plL[r][c8 * 8] = *(const bf16x8*)(pl + go);
        *(bf16x8*)&ebL[r][c8 * 8] = *(const bf16x8*)(eb + go);
    }
    __syncthreads();

    f32x4 aQ = f32x4{0.f, 0.f, 0.f, 0.f};
    f32x4 aK = f32x4{0.f, 0.f, 0.f, 0.f};
    f32x4 aV = f32x4{0.f, 0.f, 0.f, 0.f};

#pragma unroll 2
    for (int kc = 0; kc < 8; ++kc) {
        const bf16x8 aph = *(const bf16x8*)&phL[m16][kc * 32 + quad * 8];
        const bf16x8 apl = *(const bf16x8*)&plL[m16][kc * 32 + quad * 8];
        const bf16x8 aeb = *(const bf16x8*)&ebL[m16][kc * 32 + quad * 8];
        const size_t wo = ((size_t)((nb * 4 + w) * 8 + kc)) * 512 + (size_t)lane * 8;
        const bf16x8 bqh = *(const bf16x8*)(WFq_h + wo);
        const bf16x8 bql = *(const bf16x8*)(WFq_l + wo);
        const bf16x8 bkh = *(const bf16x8*)(WFk_h + wo);
        const bf16x8 bkl = *(const bf16x8*)(WFk_l + wo);
        const bf16x8 bv  = *(const bf16x8*)(WFv + wo);
        aQ = mfma16(aph, bqh, aQ);
        aQ = mfma16(apl, bqh, aQ);
        aQ = mfma16(aph, bql, aQ);
        aK = mfma16(aph, bkh, aK);
        aK = mfma16(apl, bkh, aK);
        aK = mfma16(aph, bkl, aK);
        aV = mfma16(aeb, bv, aV);
    }

    // stage accumulators f32 into LDS for the fragment transpose
#pragma unroll
    for (int r = 0; r < 4; ++r) {
        const int rl = quad * 4 + r;          // C/D row = quad*4+reg
        fQ[rl][w * 16 + m16] = aQ[r];
        fK[rl][w * 16 + m16] = aK[r];
        fV[rl][w * 16 + m16] = aV[r];
    }

    // q2/k2 row-norm partials (from f32 accumulators)
#pragma unroll
    for (int r = 0; r < 4; ++r) {
        float vq = aQ[r] * aQ[r], vk = aK[r] * aK[r];
#pragma unroll
        for (int off = 8; off >= 1; off >>= 1) {
            vq += __shfl_xor(vq, off);
            vk += __shfl_xor(vk, off);
        }
        if (m16 == 0) {
            atomicAdd(q2 + row0 + quad * 4 + r, vq);
            atomicAdd(k2 + row0 + quad * 4 + r, vk);
        }
    }

    __syncthreads();

    const int b   = row0 >> 11;
    const int sl  = row0 & 2047;
    const int tt  = sl >> 6;
    const int st  = sl >> 5;
    const int w4  = (sl >> 4) & 3;   // KF row-group
    const int mt  = (sl >> 4) & 1;   // QF row-group
    const int kc2 = (sl >> 5) & 1;   // VF t-half
    const int uh  = (sl >> 4) & 1;   // VF u-half

    if (w < 2) {
        // QF chunk kc = nb*2 + w  (hi + lo)
        const int cl = w;
        const float* src = &fQ[m16][cl * 32 + quad * 8];
        const float4 a = *(const float4*)src;
        const float4 c = *(const float4*)(src + 4);
        const float f[8] = {a.x, a.y, a.z, a.w, c.x, c.y, c.z, c.w};
        bf16x8 hi, lo;
#pragma unroll
        for (int j = 0; j < 8; ++j) {
            const bf16_t h = (bf16_t)f[j];
            hi[j] = h; lo[j] = (bf16_t)(f[j] - (float)h);
        }
        const size_t off = ((size_t)(b * 64 + st)) * 8192
                         + (size_t)(mt * 8 + nb * 2 + cl) * 512 + (size_t)lane * 8;
        *(bf16x8*)(QFh + off) = hi; *(bf16x8*)(QFl + off) = lo;
    } else {
        // KF chunk kc = nb*2 + (w-2)  (hi + lo)
        const int cl = w - 2;
        const float* src = &fK[m16][cl * 32 + quad * 8];
        const float4 a = *(const float4*)src;
        const float4 c = *(const float4*)(src + 4);
        const float f[8] = {a.x, a.y, a.z, a.w, c.x, c.y, c.z, c.w};
        bf16x8 hi, lo;
#pragma unroll
        for (int j = 0; j < 8; ++j) {
            const bf16_t h = (bf16_t)f[j];
            hi[j] = h; lo[j] = (bf16_t)(f[j] - (float)h);
        }
        const size_t off = ((size_t)(b * 32 + tt)) * 16384
                         + (size_t)(w4 * 8 + nb * 2 + cl) * 512 + (size_t)lane * 8;
        *(bf16x8*)(KFh + off) = hi; *(bf16x8*)(KFl + off) = lo;
    }

    // VF half-chunks: wave w handles nt=w with lanes 0..31 (u-half uh)
    if (lane < 32) {
        const int nt  = w;
        const int u   = uh * 32 + lane;
        const int tl0 = (lane >> 4) * 8;     // t_local base within block rows
        bf16x8 vb;
#pragma unroll
        for (int j = 0; j < 8; ++j)
            vb[j] = (bf16_t)fV[tl0 + j][nt * 16 + (lane & 15)];
        const size_t off = ((size_t)(b * 32 + tt)) * 16384
                         + (size_t)(nb * 8 + kc2 * 4 + nt) * 512 + (size_t)u * 8;
        *(bf16x8*)(VF + off) = vb;
    }
}

// ---------------------------------------------------------------------------
// K2: flash-style causal pass, triangle-paired, fragment-major operands.
// Grid = 256 blocks (32 pairs x 4 splits x 2 b), bid&7 == split*2+b so each
// XCD hosts one (split,b) class (K/V set fits its 4MiB L2).
// R16: software-pipelined.  Steady state (one basic block, branch-free):
//   scores(group j) -> Pb[q]  ||  PV(group j-1) from Pb[q^1] + vf regs
//   then vf <- V(group j); barrier; q^=1.   (Byte-identical to R16/R17.)
// ---------------------------------------------------------------------------
__global__ __launch_bounds__(256, 1) void att_flash(
    const bf16_t* __restrict__ QFh, const bf16_t* __restrict__ QFl,
    const bf16_t* __restrict__ KFh, const bf16_t* __restrict__ KFl,
    const bf16_t* __restrict__ VF, const float* __restrict__ q2,
    const float* __restrict__ k2, const float* __restrict__ gamma,
    float* __restrict__ part, float* __restrict__ out)
{
    __shared__ bf16_t Pb[2][2][32][72];   // [parity][tile-in-group][s][t]

    const int tid   = threadIdx.x;
    const int pair  = blockIdx.x >> 3;     // 0..31
    const int sub   = blockIdx.x & 7;      // == xcd class
    const int split = sub >> 1;            // 0..3
    const int b     = sub & 1;
    const int wave  = tid >> 6;
    const int lane  = tid & 63;
    const int m16   = lane & 15;
    const int quad  = lane >> 4;

    float g[8];
#pragma unroll
    for (int h = 0; h < 8; ++h) g[h] = gamma[h];

    int q = 0;

    for (int half = 0; half < 2; ++half) {
        const int st = half ? (63 - pair) : pair;
        const int s0 = st * 32;

        // Q fragments -> registers, contiguous chunk loads.
        bf16x8 aQh[2][8], aQl[2][8];
        const size_t qtile = ((size_t)(b * 64 + st)) * 8192 + (size_t)lane * 8;
#pragma unroll
        for (int mt = 0; mt < 2; ++mt)
#pragma unroll
            for (int kc = 0; kc < 8; ++kc) {
                const size_t base = qtile + (size_t)(mt * 8 + kc) * 512;
                aQh[mt][kc] = *(const bf16x8*)(QFh + base);
                aQl[mt][kc] = *(const bf16x8*)(QFl + base);
            }

        float q2r[2][4];
#pragma unroll
        for (int mt = 0; mt < 2; ++mt)
#pragma unroll
            for (int r = 0; r < 4; ++r)
                q2r[mt][r] = q2[b * SS + s0 + mt * 16 + quad * 4 + r];

        const int n_tiles = (s0 + 31) / 64 + 1;

        for (int h = 0; h < HH; ++h) {
            int rep = 0;
            while (g[rep] != g[h]) ++rep;
            if (rep != h) continue;
            const float cexp = 1.0f / (2.0f * g[h] - 1e-6f);

            f32x4 O[2][4];
#pragma unroll
            for (int mt = 0; mt < 2; ++mt)
#pragma unroll
                for (int nt = 0; nt < 4; ++nt)
                    O[mt][nt] = f32x4{0.f, 0.f, 0.f, 0.f};

            bf16x8 vf[2][2][4];   // pending group's V [tile][kc2][nt]

            // --- helpers (inlined; constant slot args propagate) ---
            auto SCORES_DUAL = [&](int tiA, int tiB) {
                const int tgA = tiA * 64 + wave * 16 + m16;
                const int tgB = tiB * 64 + wave * 16 + m16;
                const size_t tileA = ((size_t)(b * 32 + tiA)) * 16384
                                   + (size_t)wave * 4096 + (size_t)lane * 8;
                const size_t tileB = ((size_t)(b * 32 + tiB)) * 16384
                                   + (size_t)wave * 4096 + (size_t)lane * 8;
                const float k2A = k2[b * SS + tgA];
                const float k2B = k2[b * SS + tgB];
                f32x4 aA0 = f32x4{0.f, 0.f, 0.f, 0.f};
                f32x4 aA1 = f32x4{0.f, 0.f, 0.f, 0.f};
                f32x4 aB0 = f32x4{0.f, 0.f, 0.f, 0.f};
                f32x4 aB1 = f32x4{0.f, 0.f, 0.f, 0.f};
#pragma unroll
                for (int kc = 0; kc < 8; ++kc) {
                    const bf16x8 bhA = *(const bf16x8*)(KFh + tileA + (size_t)kc * 512);
                    const bf16x8 blA = *(const bf16x8*)(KFl + tileA + (size_t)kc * 512);
                    const bf16x8 bhB = *(const bf16x8*)(KFh + tileB + (size_t)kc * 512);
                    const bf16x8 blB = *(const bf16x8*)(KFl + tileB + (size_t)kc * 512);
                    aA0 = mfma16(aQh[0][kc], bhA, aA0);
                    aA1 = mfma16(aQh[1][kc], bhA, aA1);
                    aB0 = mfma16(aQh[0][kc], bhB, aB0);
                    aB1 = mfma16(aQh[1][kc], bhB, aB1);
                    aA0 = mfma16(aQl[0][kc], bhA, aA0);
                    aA1 = mfma16(aQl[1][kc], bhA, aA1);
                    aB0 = mfma16(aQl[0][kc], bhB, aB0);
                    aB1 = mfma16(aQl[1][kc], bhB, aB1);
                    aA0 = mfma16(aQh[0][kc], blA, aA0);
                    aA1 = mfma16(aQh[1][kc], blA, aA1);
                    aB0 = mfma16(aQh[0][kc], blB, aB0);
                    aB1 = mfma16(aQh[1][kc], blB, aB1);
                }
#pragma unroll
                for (int mt = 0; mt < 2; ++mt) {
#pragma unroll
                    for (int r = 0; r < 4; ++r) {
                        const int sl = mt * 16 + quad * 4 + r;
                        const int sg = s0 + sl;
                        float dA = q2r[mt][r] + k2A - 2.0f * (mt ? aA1[r] : aA0[r]);
                        dA = fmaxf(dA, 0.0f);
                        Pb[q][0][sl][wave * 16 + m16] =
                            (bf16_t)((tgA <= sg) ? __expf(cexp * dA) : 0.0f);
                        float dB = q2r[mt][r] + k2B - 2.0f * (mt ? aB1[r] : aB0[r]);
                        dB = fmaxf(dB, 0.0f);
                        Pb[q][1][sl][wave * 16 + m16] =
                            (bf16_t)((tgB <= sg) ? __expf(cexp * dB) : 0.0f);
                    }
                }
            };

            auto SCORES_SINGLE = [&](int tiA) {
                const int tg = tiA * 64 + wave * 16 + m16;
                const size_t tile = ((size_t)(b * 32 + tiA)) * 16384
                                  + (size_t)wave * 4096 + (size_t)lane * 8;
                const float k2v = k2[b * SS + tg];
                f32x4 acc0 = f32x4{0.f, 0.f, 0.f, 0.f};
                f32x4 acc1 = f32x4{0.f, 0.f, 0.f, 0.f};
#pragma unroll
                for (int kc = 0; kc < 8; ++kc) {
                    const bf16x8 bh = *(const bf16x8*)(KFh + tile + (size_t)kc * 512);
                    const bf16x8 bl = *(const bf16x8*)(KFl + tile + (size_t)kc * 512);
                    acc0 = mfma16(aQh[0][kc], bh, acc0);
                    acc1 = mfma16(aQh[1][kc], bh, acc1);
                    acc0 = mfma16(aQl[0][kc], bh, acc0);
                    acc1 = mfma16(aQl[1][kc], bh, acc1);
                    acc0 = mfma16(aQh[0][kc], bl, acc0);
                    acc1 = mfma16(aQh[1][kc], bl, acc1);
                }
#pragma unroll
                for (int mt = 0; mt < 2; ++mt) {
#pragma unroll
                    for (int r = 0; r < 4; ++r) {
                        const int sl = mt * 16 + quad * 4 + r;
                        const int sg = s0 + sl;
                        float d2 = q2r[mt][r] + k2v - 2.0f * (mt ? acc1[r] : acc0[r]);
                        d2 = fmaxf(d2, 0.0f);
                        Pb[q][0][sl][wave * 16 + m16] =
                            (bf16_t)((tg <= sg) ? __expf(cexp * d2) : 0.0f);
                    }
                }
            };

            auto PV_ONE = [&](int slot) {    // always called with constant slot
#pragma unroll
                for (int kc2 = 0; kc2 < 2; ++kc2) {
                    const bf16x8 pa0 = *(const bf16x8*)
                        &Pb[q ^ 1][slot][m16][kc2 * 32 + quad * 8];
                    const bf16x8 pa1 = *(const bf16x8*)
                        &Pb[q ^ 1][slot][m16 + 16][kc2 * 32 + quad * 8];
#pragma unroll
                    for (int nt = 0; nt < 4; ++nt) {
                        O[0][nt] = mfma16(pa0, vf[slot][kc2][nt], O[0][nt]);
                        O[1][nt] = mfma16(pa1, vf[slot][kc2][nt], O[1][nt]);
                    }
                }
            };

            auto LOADV = [&](int slot, int tiX) {   // constant slot
                const size_t tile = ((size_t)(b * 32 + tiX)) * 16384
                                  + (size_t)wave * 4096 + (size_t)lane * 8;
#pragma unroll
                for (int kc2 = 0; kc2 < 2; ++kc2)
#pragma unroll
                    for (int nt = 0; nt < 4; ++nt)
                        vf[slot][kc2][nt] = *(const bf16x8*)(
                            VF + tile + (size_t)(kc2 * 4 + nt) * 512);
            };

            int ti = split;
            bool pendDual = false;

            if (ti < n_tiles) {
                // ---- prologue: first group, no pending PV ----
                const bool dual0 = (ti + TSPLIT < n_tiles);
                if (dual0) {
                    SCORES_DUAL(ti, ti + TSPLIT);
                    LOADV(0, ti); LOADV(1, ti + TSPLIT);
                } else {
                    SCORES_SINGLE(ti);
                    LOADV(0, ti);
                }
                __syncthreads();
                q ^= 1;
                pendDual = dual0;
                ti += dual0 ? 2 * TSPLIT : TSPLIT;

                // ---- steady state: dual scores || dual PV, one BB ----
                while (ti + TSPLIT < n_tiles) {
                    SCORES_DUAL(ti, ti + TSPLIT);
                    PV_ONE(0); PV_ONE(1);
                    LOADV(0, ti); LOADV(1, ti + TSPLIT);
                    __syncthreads();
                    q ^= 1;
                    ti += 2 * TSPLIT;
                }

                // ---- optional final single group (pending is dual here) ----
                if (ti < n_tiles) {
                    SCORES_SINGLE(ti);
                    PV_ONE(0); PV_ONE(1);
                    LOADV(0, ti);
                    __syncthreads();
                    q ^= 1;
                    pendDual = false;
                    ti += TSPLIT;
                }

                // ---- drain pending PV ----
                PV_ONE(0);
                if (pendDual) PV_ONE(1);
            }

            // plain stores: split0 -> out slab, splits 1..3 -> ws partials
            float* dst = (split == 0)
                ? out  + (((size_t)b * HH + h) * SS + s0) * DD
                : part + ((((size_t)(split - 1) * BB + b) * HH + h) * SS + s0) * DD;
#pragma unroll
            for (int mt = 0; mt < 2; ++mt)
#pragma unroll
                for (int nt = 0; nt < 4; ++nt)
#pragma unroll
                    for (int r = 0; r < 4; ++r)
                        dst[(size_t)(mt * 16 + quad * 4 + r) * DD
                            + wave * 64 + nt * 16 + m16] = O[mt][nt][r];
        }
    }
}

// ---------------------------------------------------------------------------
// K3: reduce split partials into rep heads and broadcast to duplicate-gamma
// heads.  out[b][rep] already holds split0; add 3 partial slabs, write to
// every head sharing that gamma.
// ---------------------------------------------------------------------------
__global__ __launch_bounds__(256) void att_reduce_bcast(
    const float* __restrict__ gamma, const float* __restrict__ part,
    float* __restrict__ out)
{
    const int j = blockIdx.x * 256 + threadIdx.x;   // float4 index within slab
    const int b = blockIdx.y;
    const int slab = SS * DD / 4;

    float g[8];
#pragma unroll
    for (int h = 0; h < 8; ++h) g[h] = gamma[h];

    const float4* pp = (const float4*)part;
    float4* o4 = (float4*)out;

    float4 repval{0.f, 0.f, 0.f, 0.f};
    int last_rep = -1;
#pragma unroll
    for (int h = 0; h < HH; ++h) {
        int rep = 0;
        while (g[rep] != g[h]) ++rep;
        float4* o = o4 + ((size_t)(b * HH + h)) * slab + j;
        if (rep == h) {
            float4 v = *o;
#pragma unroll
            for (int k = 0; k < TSPLIT - 1; ++k) {
                const float4 pv = pp[(((size_t)k * BB + b) * HH + h) * slab + j];
                v.x += pv.x; v.y += pv.y; v.z += pv.z; v.w += pv.w;
            }
            *o = v; repval = v; last_rep = h;
        } else {
            if (last_rep != rep) {
                repval = o4[((size_t)(b * HH + rep)) * slab + j];
                last_rep = rep;
            }
            *o = repval;
        }
    }
}

extern "C" void kernel_launch(void* const* d_in, const int* in_sizes, int n_in,
                              void* d_out, int out_size, void* d_ws, size_t ws_size,
                              hipStream_t stream) {
    (void)in_sizes; (void)n_in; (void)out_size; (void)ws_size;
    // inputs: 0=x (unused), 1=e, 2=p, 3=W_q, 4=W_k, 5=W_v, 6=gamma
    const float* e     = (const float*)d_in[1];
    const float* p     = (const float*)d_in[2];
    const float* Wq    = (const float*)d_in[3];
    const float* Wk    = (const float*)d_in[4];
    const float* Wv    = (const float*)d_in[5];
    const float* gamma = (const float*)d_in[6];

    const size_t NROW = (size_t)BSR * DD;   // 1048576 elements
    bf16_t* WFq_h = (bf16_t*)d_ws;          // fragment-major weights
    bf16_t* WFq_l = WFq_h + DD * DD;
    bf16_t* WFk_h = WFq_l + DD * DD;
    bf16_t* WFk_l = WFk_h + DD * DD;
    bf16_t* WFv   = WFk_l + DD * DD;
    float*  q2    = (float*)(WFv + DD * DD);
    float*  k2    = q2 + BSR;
    bf16_t* QFh   = (bf16_t*)(k2 + BSR);    // fragment-major Q/K/V
    bf16_t* QFl   = QFh + NROW;
    bf16_t* KFh   = QFl + NROW;
    bf16_t* KFl   = KFh + NROW;
    bf16_t* VF    = KFl + NROW;
    bf16_t* ph    = VF + NROW;              // pre-repacked A operands
    bf16_t* pl    = ph + NROW;
    bf16_t* eb    = pl + NROW;
    float*  part  = (float*)(eb + NROW);    // 3 x B x H x S x D f32 (~101MB)

    float* out = (float*)d_out;

    att_wtrans<<<dim3(49 + BSR / 16), dim3(256), 0, stream>>>(
        Wq, Wk, Wv, p, e, WFq_h, WFq_l, WFk_h, WFk_l, WFv, ph, pl, eb, q2, k2);

    att_gemm_qkv<<<dim3((BSR / 16) * 4), dim3(256), 0, stream>>>(
        ph, pl, eb, WFq_h, WFq_l, WFk_h, WFk_l, WFv, QFh, QFl, KFh, KFl, VF, q2, k2);

    att_flash<<<dim3(32 * TSPLIT * BB), dim3(256), 0, stream>>>(
        QFh, QFl, KFh, KFl, VF, q2, k2, gamma, part, out);

    att_reduce_bcast<<<dim3(SS * DD / 4 / 256, BB), dim3(256), 0, stream>>>(
        gamma, part, out);
}